// Round 4
// baseline (936.656 us; speedup 1.0000x reference)
//
#include <hip/hip_runtime.h>
#include <hip/hip_bf16.h>
#include <cstdint>
#include <cstddef>

#define N_EXPERTS 8
#define HIDDEN    2048
#define EDIM      1408
#define UPCOLS    2816
#define NTOK      8192
#define CAP       8192
#define MAXT      72    // max 256-row M-tiles: (16384 + 8*255)/256 rounded up
#define NS_UP     11    // EDIM/128 gate-col slices for gemm_up (128 gate + 128 up per block)
#define NS_DN     8     // HIDDEN/256 col slices for gemm_down
#define GUP       3     // m-group size (A 3x1MB + B 1MB ~= L2)
#define GDN       4
#define NT_UP     32    // HIDDEN/64 K-tiles
#define NT_DN     22    // EDIM/64 K-tiles

typedef __bf16 bf16x8 __attribute__((ext_vector_type(8)));
typedef __bf16 bf16x4 __attribute__((ext_vector_type(4)));
typedef float  f32x4  __attribute__((ext_vector_type(4)));

// ---- workspace layout (bytes) ----
#define EPOS_OFF  4096
#define TOK_OFF   (EPOS_OFF + (size_t)NTOK * 2 * 4)
#define W_OFF     (TOK_OFF + (size_t)CAP * N_EXPERTS * 4)
#define XBF_OFF   (W_OFF + (size_t)CAP * N_EXPERTS * 4)
#define UPT_OFF   (XBF_OFF + (size_t)NTOK * HIDDEN * 2)
#define DNT_OFF   (UPT_OFF + (size_t)N_EXPERTS * UPCOLS * HIDDEN * 2)
#define HACT_OFF  (DNT_OFF + (size_t)N_EXPERTS * HIDDEN * EDIM * 2)
#define HACT_ROWS ((size_t)MAXT * 256)   // 18432
#define WS_NEEDED (HACT_OFF + HACT_ROWS * EDIM * 2)
// ybuf [HACT_ROWS][HIDDEN] bf16 (75.5MB) aliases the upT region (92MB):
// upT is dead once gemm_up finishes; gemm_down writes ybuf, combine reads it.
#define YBUF_OFF  UPT_OFF

// meta (ints): [0..8) raw counts, [8] ntiles, [16..24) h-row offsets,
//              [32..104) tile->expert, [192..264) tile->local row0

__device__ __forceinline__ void gload16(const void* g, void* l) {
  __builtin_amdgcn_global_load_lds(
      (const __attribute__((address_space(1))) void*)g,
      (__attribute__((address_space(3))) void*)l, 16, 0, 0);
}

__global__ void build_entries(const int* __restrict__ idx,
                              const float* __restrict__ sc,
                              int* __restrict__ meta,
                              int* __restrict__ toks,
                              float* __restrict__ wts,
                              int* __restrict__ epos) {
  int t = blockIdx.x * blockDim.x + threadIdx.x;
  if (t >= NTOK) return;
  int e0 = idx[2 * t] & 7, e1 = idx[2 * t + 1] & 7;   // int32 per harness contract
  float s0 = sc[2 * t], s1 = sc[2 * t + 1];
  if (e0 == e1) {
    int p = atomicAdd(&meta[e0], 1);
    toks[e0 * CAP + p] = t; wts[e0 * CAP + p] = s0 + s1;
    epos[2 * t] = (e0 << 16) | p; epos[2 * t + 1] = -1;
  } else {
    int p0 = atomicAdd(&meta[e0], 1);
    toks[e0 * CAP + p0] = t; wts[e0 * CAP + p0] = s0;
    int p1 = atomicAdd(&meta[e1], 1);
    toks[e1 * CAP + p1] = t; wts[e1 * CAP + p1] = s1;
    epos[2 * t] = (e0 << 16) | p0; epos[2 * t + 1] = (e1 << 16) | p1;
  }
}

// pads each expert to 256-row tiles now (256^2 GEMM blocks)
__global__ void finalize_meta(int* __restrict__ meta,
                              int* __restrict__ toks,
                              float* __restrict__ wts) {
  __shared__ int c[8], pc[8];
  int tid = threadIdx.x;
  if (tid < 8) { c[tid] = meta[tid]; pc[tid] = ((c[tid] + 255) >> 8) << 8; }
  __syncthreads();
  if (tid == 0) {
    int off = 0, t = 0;
    for (int e = 0; e < 8; e++) {
      meta[16 + e] = off;
      int nt = pc[e] >> 8;
      for (int i = 0; i < nt; i++) { meta[32 + t] = e; meta[192 + t] = i * 256; t++; }
      off += pc[e];
    }
    meta[8] = t;
  }
  // pad entries to tile multiple with weight-0 token-0 rows
  for (int e = 0; e < 8; e++)
    for (int i = c[e] + tid; i < pc[e]; i += blockDim.x) {
      toks[e * CAP + i] = 0; wts[e * CAP + i] = 0.f;
    }
}

__global__ void cast_x(const float4* __restrict__ in, __bf16* __restrict__ o) {
  size_t i = (size_t)blockIdx.x * blockDim.x + threadIdx.x;
  float4 v = in[i];
  bf16x4 r = { (__bf16)v.x, (__bf16)v.y, (__bf16)v.z, (__bf16)v.w };
  ((bf16x4*)o)[i] = r;
}

// in: [E][K][N] fp32 -> out: [E][N][K] bf16  (N-major so GEMM B-frags are K-contiguous)
__global__ void transpose_cast(const float* __restrict__ in, __bf16* __restrict__ out,
                               int K, int N) {
  __shared__ float t[32][33];
  const size_t ebase = (size_t)blockIdx.z * K * N;
  const float* src = in + ebase;
  __bf16* dst = out + ebase;
  int x0 = blockIdx.x * 32, y0 = blockIdx.y * 32;
  int tx = threadIdx.x, ty = threadIdx.y;
#pragma unroll
  for (int i = 0; i < 4; i++)
    t[ty + 8 * i][tx] = src[(size_t)(y0 + ty + 8 * i) * N + x0 + tx];
  __syncthreads();
#pragma unroll
  for (int i = 0; i < 4; i++)
    dst[(size_t)(x0 + ty + 8 * i) * K + y0 + tx] = (__bf16)t[tx][ty + 8 * i];
}

// ============================================================================
// 256^2-tile grouped GEMMs: 512 threads (8 waves, 2M x 4N), BK=64, per-wave
// output 128x64. LDS 128 KB: A[2buf][2half][128][64] + B[...] bf16, XOR-slot
// swizzled (slot = (kk*4+quad) ^ (row&7), rows are 128B). Pipeline per K-tile:
// issue 8 global_load_lds for tile k+1 -> s_waitcnt vmcnt(8) (waits only the
// 8 OLD loads; the new 8 stay in flight under compute) -> barrier -> 4 phases
// {12 ds_read_b128; barrier; setprio(1); 16 MFMA; setprio(0); barrier}.
// Writes to a buffer only issue after the barrier that follows its last read.
// Expert->XCD affinity rank decode identical to round-3 (proven -3.4x FETCH).
// ============================================================================

__global__ __launch_bounds__(512, 2) void gemm_up(
    const __bf16* __restrict__ xb, const __bf16* __restrict__ upT,
    const int* __restrict__ meta, const int* __restrict__ toks,
    __bf16* __restrict__ hact) {
  const int rank = (blockIdx.x & 7) * (MAXT * NS_UP / 8) + (blockIdx.x >> 3);
  const int vt = rank / NS_UP;
  if (vt >= meta[8]) return;
  const int e = meta[32 + vt];
  const int tb = vt - (meta[192 + vt] >> 8);
  const int tiles_e = (meta[e] + 255) >> 8;
  int rem = rank - NS_UP * tb;
  int g = 0, tleft = tiles_e;
  for (;;) {
    int gsz = tleft < GUP ? tleft : GUP;
    int span = NS_UP * gsz;
    if (rem < span) break;
    rem -= span; tleft -= GUP; g++;
  }
  const int gsz = tleft < GUP ? tleft : GUP;
  const int s = rem / gsz, tix = rem - s * gsz;
  const int row0 = (g * GUP + tix) * 256;
  const int hbase = meta[16 + e];
  const int n0 = s * 128;                    // gate cols [n0,n0+128), up same +EDIM

  __shared__ __attribute__((aligned(16))) char lds[131072];

  const int tid = threadIdx.x;
  const int lane = tid & 63, wave = tid >> 6;
  const int wm = wave >> 2, wn = wave & 3;
  const int l15 = lane & 15, quad = lane >> 4;
  const int srow = tid >> 3;                 // staging row 0..63
  const int gch = (tid & 7) ^ (srow & 7);    // XOR-swizzled source chunk

  const __bf16* upE = upT + (size_t)e * UPCOLS * HIDDEN;

  // staging offsets: A rows {row0 + r*64 + srow}, B-tile rows {r*64 + srow}
  size_t aoff[4], boff[4];
#pragma unroll
  for (int r = 0; r < 4; r++) {
    int row = row0 + r * 64 + srow;
    int tok = toks[e * CAP + row];
    aoff[r] = (size_t)tok * HIDDEN + gch * 8;
  }
#pragma unroll
  for (int j = 0; j < 4; j++) {
    int grow = (srow < 32) ? (n0 + 32 * j + srow)
                           : (EDIM + n0 + 32 * j + (srow - 32));
    boff[j] = (size_t)grow * HIDDEN + gch * 8;
  }

  f32x4 acc[2][2][4][2] = {};                // [rowhalf][gate/up][mi][ni]

  const int sl0 = (quad ^ (l15 & 7)) * 16;
  const int sl1 = ((4 + quad) ^ (l15 & 7)) * 16;
  const int aRowBase = wm * 16384 + l15 * 128;
  const int bRowBase = 65536 + (wn >> 1) * 16384 + ((wn & 1) * 64 + l15) * 128;

#define STAGE_UP(buf, k0) do {                                          \
    char* _a = lds + (buf) * 32768;                                     \
    char* _bb = lds + 65536 + (buf) * 32768;                            \
    _Pragma("unroll")                                                   \
    for (int r = 0; r < 4; r++)                                         \
      gload16(xb + aoff[r] + (k0), _a + r * 8192 + tid * 16);           \
    _Pragma("unroll")                                                   \
    for (int r = 0; r < 4; r++)                                         \
      gload16(upE + boff[r] + (k0), _bb + r * 8192 + tid * 16);         \
  } while (0)

#define PHASE_UP(cbuf, rh, ch) do {                                     \
    const char* _l = lds + (cbuf) * 32768;                              \
    bf16x8 a0[4], a1[4], b0[2], b1[2];                                  \
    _Pragma("unroll")                                                   \
    for (int mi = 0; mi < 4; mi++) {                                    \
      int rb = aRowBase + (rh) * 8192 + mi * 2048;                      \
      a0[mi] = *(const bf16x8*)(_l + rb + sl0);                         \
      a1[mi] = *(const bf16x8*)(_l + rb + sl1);                         \
    }                                                                   \
    _Pragma("unroll")                                                   \
    for (int ni = 0; ni < 2; ni++) {                                    \
      int rb = bRowBase + (ch) * 4096 + ni * 2048;                      \
      b0[ni] = *(const bf16x8*)(_l + rb + sl0);                         \
      b1[ni] = *(const bf16x8*)(_l + rb + sl1);                         \
    }                                                                   \
    __builtin_amdgcn_s_barrier();                                       \
    __builtin_amdgcn_s_setprio(1);                                      \
    _Pragma("unroll")                                                   \
    for (int mi = 0; mi < 4; mi++)                                      \
      _Pragma("unroll")                                                 \
      for (int ni = 0; ni < 2; ni++) {                                  \
        acc[rh][ch][mi][ni] = __builtin_amdgcn_mfma_f32_16x16x32_bf16(  \
            a0[mi], b0[ni], acc[rh][ch][mi][ni], 0, 0, 0);              \
        acc[rh][ch][mi][ni] = __builtin_amdgcn_mfma_f32_16x16x32_bf16(  \
            a1[mi], b1[ni], acc[rh][ch][mi][ni], 0, 0, 0);              \
      }                                                                 \
    __builtin_amdgcn_s_setprio(0);                                      \
    __builtin_amdgcn_s_barrier();                                       \
  } while (0)

  STAGE_UP(0, 0);
#pragma unroll 1
  for (int kt = 0; kt < NT_UP; ++kt) {
    const int c = kt & 1;
    if (kt + 1 < NT_UP) {
      STAGE_UP(c ^ 1, (kt + 1) * 64);
      asm volatile("s_waitcnt vmcnt(8)" ::: "memory");
    } else {
      asm volatile("s_waitcnt vmcnt(0)" ::: "memory");
    }
    __builtin_amdgcn_s_barrier();
    PHASE_UP(c, 0, 0); PHASE_UP(c, 0, 1);
    PHASE_UP(c, 1, 0); PHASE_UP(c, 1, 1);
  }
#undef STAGE_UP
#undef PHASE_UP

#pragma unroll
  for (int rh = 0; rh < 2; rh++)
#pragma unroll
    for (int mi = 0; mi < 4; mi++)
#pragma unroll
      for (int v = 0; v < 4; v++) {
        int m = hbase + row0 + wm * 128 + rh * 64 + mi * 16 + quad * 4 + v;
#pragma unroll
        for (int ni = 0; ni < 2; ni++) {
          int n = n0 + wn * 32 + ni * 16 + l15;
          float gg = acc[rh][0][mi][ni][v];
          float uu = acc[rh][1][mi][ni][v];
          float act = gg / (1.f + __expf(-gg)) * uu;
          hact[(size_t)m * EDIM + n] = (__bf16)act;
        }
      }
}

__global__ __launch_bounds__(512, 2) void gemm_down(
    const __bf16* __restrict__ hact, const __bf16* __restrict__ dnT,
    const int* __restrict__ meta, const float* __restrict__ wts,
    __bf16* __restrict__ ybuf) {
  const int rank = (blockIdx.x & 7) * (MAXT * NS_DN / 8) + (blockIdx.x >> 3);
  const int vt = rank / NS_DN;
  if (vt >= meta[8]) return;
  const int e = meta[32 + vt];
  const int tb = vt - (meta[192 + vt] >> 8);
  const int tiles_e = (meta[e] + 255) >> 8;
  int rem = rank - NS_DN * tb;
  int g = 0, tleft = tiles_e;
  for (;;) {
    int gsz = tleft < GDN ? tleft : GDN;
    int span = NS_DN * gsz;
    if (rem < span) break;
    rem -= span; tleft -= GDN; g++;
  }
  const int gsz = tleft < GDN ? tleft : GDN;
  const int s = rem / gsz, tix = rem - s * gsz;
  const int row0 = (g * GDN + tix) * 256;
  const int hbase = meta[16 + e];
  const int n0 = s * 256;

  __shared__ __attribute__((aligned(16))) char lds[131072];

  const int tid = threadIdx.x;
  const int lane = tid & 63, wave = tid >> 6;
  const int wm = wave >> 2, wn = wave & 3;
  const int l15 = lane & 15, quad = lane >> 4;
  const int srow = tid >> 3;
  const int gch = (tid & 7) ^ (srow & 7);

  const __bf16* dnE = dnT + (size_t)e * HIDDEN * EDIM;

  size_t aoff[4], boff[4];
#pragma unroll
  for (int r = 0; r < 4; r++) {
    aoff[r] = (size_t)(hbase + row0 + r * 64 + srow) * EDIM + gch * 8;
    boff[r] = (size_t)(n0 + r * 64 + srow) * EDIM + gch * 8;
  }

  f32x4 acc[2][2][4][2] = {};

  const int sl0 = (quad ^ (l15 & 7)) * 16;
  const int sl1 = ((4 + quad) ^ (l15 & 7)) * 16;
  const int aRowBase = wm * 16384 + l15 * 128;
  const int bRowBase = 65536 + (wn >> 1) * 16384 + ((wn & 1) * 64 + l15) * 128;

#define STAGE_DN(buf, k0) do {                                          \
    char* _a = lds + (buf) * 32768;                                     \
    char* _bb = lds + 65536 + (buf) * 32768;                            \
    _Pragma("unroll")                                                   \
    for (int r = 0; r < 4; r++)                                         \
      gload16(hact + aoff[r] + (k0), _a + r * 8192 + tid * 16);         \
    _Pragma("unroll")                                                   \
    for (int r = 0; r < 4; r++)                                         \
      gload16(dnE + boff[r] + (k0), _bb + r * 8192 + tid * 16);         \
  } while (0)

#define PHASE_DN(cbuf, rh, ch) do {                                     \
    const char* _l = lds + (cbuf) * 32768;                              \
    bf16x8 a0[4], a1[4], b0[2], b1[2];                                  \
    _Pragma("unroll")                                                   \
    for (int mi = 0; mi < 4; mi++) {                                    \
      int rb = aRowBase + (rh) * 8192 + mi * 2048;                      \
      a0[mi] = *(const bf16x8*)(_l + rb + sl0);                         \
      a1[mi] = *(const bf16x8*)(_l + rb + sl1);                         \
    }                                                                   \
    _Pragma("unroll")                                                   \
    for (int ni = 0; ni < 2; ni++) {                                    \
      int rb = bRowBase + (ch) * 4096 + ni * 2048;                      \
      b0[ni] = *(const bf16x8*)(_l + rb + sl0);                         \
      b1[ni] = *(const bf16x8*)(_l + rb + sl1);                         \
    }                                                                   \
    __builtin_amdgcn_s_barrier();                                       \
    __builtin_amdgcn_s_setprio(1);                                      \
    _Pragma("unroll")                                                   \
    for (int mi = 0; mi < 4; mi++)                                      \
      _Pragma("unroll")                                                 \
      for (int ni = 0; ni < 2; ni++) {                                  \
        acc[rh][ch][mi][ni] = __builtin_amdgcn_mfma_f32_16x16x32_bf16(  \
            a0[mi], b0[ni], acc[rh][ch][mi][ni], 0, 0, 0);              \
        acc[rh][ch][mi][ni] = __builtin_amdgcn_mfma_f32_16x16x32_bf16(  \
            a1[mi], b1[ni], acc[rh][ch][mi][ni], 0, 0, 0);              \
      }                                                                 \
    __builtin_amdgcn_s_setprio(0);                                      \
    __builtin_amdgcn_s_barrier();                                       \
  } while (0)

  STAGE_DN(0, 0);
#pragma unroll 1
  for (int kt = 0; kt < NT_DN; ++kt) {
    const int c = kt & 1;
    if (kt + 1 < NT_DN) {
      STAGE_DN(c ^ 1, (kt + 1) * 64);
      asm volatile("s_waitcnt vmcnt(8)" ::: "memory");
    } else {
      asm volatile("s_waitcnt vmcnt(0)" ::: "memory");
    }
    __builtin_amdgcn_s_barrier();
    PHASE_DN(c, 0, 0); PHASE_DN(c, 0, 1);
    PHASE_DN(c, 1, 0); PHASE_DN(c, 1, 1);
  }
#undef STAGE_DN
#undef PHASE_DN

#pragma unroll
  for (int rh = 0; rh < 2; rh++)
#pragma unroll
    for (int mi = 0; mi < 4; mi++)
#pragma unroll
      for (int v = 0; v < 4; v++) {
        int rloc = row0 + wm * 128 + rh * 64 + mi * 16 + quad * 4 + v;
        float w = wts[e * CAP + rloc];
        size_t gb = (size_t)(hbase + rloc) * HIDDEN;
#pragma unroll
        for (int ni = 0; ni < 2; ni++) {
#pragma unroll
          for (int ch = 0; ch < 2; ch++) {
            int n = n0 + wn * 64 + ch * 32 + ni * 16 + l15;
            ybuf[gb + n] = (__bf16)(acc[rh][ch][mi][ni][v] * w);
          }
        }
      }
}

// per token: out[t] = ybuf[row(entry0)] + ybuf[row(entry1)]  (fp32 out)
__global__ __launch_bounds__(256) void combine(
    const __bf16* __restrict__ ybuf, const int* __restrict__ epos,
    const int* __restrict__ meta, float* __restrict__ out) {
  const int t = blockIdx.x;
  const int c = threadIdx.x * 8;  // 256 threads x 8 elems = 2048 cols
  const int p0 = epos[2 * t], p1 = epos[2 * t + 1];
  const int e0 = p0 >> 16;
  const size_t g0 = (size_t)(meta[16 + e0] + (p0 & 0xffff)) * HIDDEN;
  bf16x8 y0 = *(const bf16x8*)(ybuf + g0 + c);
  float acc[8];
#pragma unroll
  for (int j = 0; j < 8; j++) acc[j] = (float)y0[j];
  if (p1 >= 0) {
    const int e1 = p1 >> 16;
    const size_t g1 = (size_t)(meta[16 + e1] + (p1 & 0xffff)) * HIDDEN;
    bf16x8 y1 = *(const bf16x8*)(ybuf + g1 + c);
#pragma unroll
    for (int j = 0; j < 8; j++) acc[j] += (float)y1[j];
  }
  float4* o = (float4*)(out + (size_t)t * HIDDEN + c);
  o[0] = make_float4(acc[0], acc[1], acc[2], acc[3]);
  o[1] = make_float4(acc[4], acc[5], acc[6], acc[7]);
}

extern "C" void kernel_launch(void* const* d_in, const int* in_sizes, int n_in,
                              void* d_out, int out_size, void* d_ws, size_t ws_size,
                              hipStream_t stream) {
  const float* x = (const float*)d_in[0];
  const int* idx = (const int*)d_in[1];     // integer inputs arrive as int32
  const float* sc = (const float*)d_in[2];
  const float* up = (const float*)d_in[3];
  const float* dn = (const float*)d_in[4];
  float* out = (float*)d_out;
  char* ws = (char*)d_ws;

  if (ws_size < WS_NEEDED) return;  // diagnosable clean failure

  int* meta = (int*)ws;
  int* epos = (int*)(ws + EPOS_OFF);
  int* toks = (int*)(ws + TOK_OFF);
  float* wts = (float*)(ws + W_OFF);
  __bf16* xb = (__bf16*)(ws + XBF_OFF);
  __bf16* upT = (__bf16*)(ws + UPT_OFF);
  __bf16* dnT = (__bf16*)(ws + DNT_OFF);
  __bf16* hact = (__bf16*)(ws + HACT_OFF);
  __bf16* ybuf = (__bf16*)(ws + YBUF_OFF);   // aliases upT (dead after gemm_up)

  hipMemsetAsync(meta, 0, 64, stream);

  build_entries<<<NTOK / 256, 256, 0, stream>>>(idx, sc, meta, toks, wts, epos);
  finalize_meta<<<1, 256, 0, stream>>>(meta, toks, wts);
  cast_x<<<(NTOK * HIDDEN / 4) / 256, 256, 0, stream>>>((const float4*)x, xb);
  dim3 tb(32, 8);
  transpose_cast<<<dim3(UPCOLS / 32, HIDDEN / 32, N_EXPERTS), tb, 0, stream>>>(up, upT, HIDDEN, UPCOLS);
  transpose_cast<<<dim3(HIDDEN / 32, EDIM / 32, N_EXPERTS), tb, 0, stream>>>(dn, dnT, EDIM, HIDDEN);
  gemm_up<<<MAXT * NS_UP, 512, 0, stream>>>(xb, upT, meta, toks, hact);
  gemm_down<<<MAXT * NS_DN, 512, 0, stream>>>(hact, dnT, meta, wts, ybuf);
  combine<<<NTOK, 256, 0, stream>>>(ybuf, epos, meta, out);
}